// Round 1
// baseline (1502.729 us; speedup 1.0000x reference)
//
#include <hip/hip_runtime.h>

#define D 128
#define NB 8

// ---------------- scatter: msg[dst] += h[src], deg[dst] += 1 ----------------
template<bool WITH_DEG>
__global__ __launch_bounds__(256) void scatter_kernel(
    const float* __restrict__ h,
    const int*   __restrict__ src,
    const int*   __restrict__ dst,
    float*       __restrict__ msg,
    float*       __restrict__ deg,
    int n_edges)
{
    const int lane   = threadIdx.x & 63;
    const int wave   = (blockIdx.x * blockDim.x + threadIdx.x) >> 6;
    const int nwaves = (gridDim.x * blockDim.x) >> 6;

    for (int e = wave; e < n_edges; e += nwaves) {
        const int s = src[e];
        const int d = dst[e];
        const float* hs = h   + (size_t)s * D;
        float*       md = msg + (size_t)d * D;
        // 64 lanes x 2 floats = 128 floats, coalesced 512B
        float2 v = *reinterpret_cast<const float2*>(hs + lane * 2);
        atomicAdd(md + lane * 2    , v.x);
        atomicAdd(md + lane * 2 + 1, v.y);
        if (WITH_DEG && lane == 0) atomicAdd(deg + d, 1.0f);
    }
}

// ------------- fused: m = msg/max(deg,1); out = relu([h,m] @ W + b) ---------
__global__ __launch_bounds__(128) void sage_gemm_kernel(
    const float* __restrict__ h,
    const float* __restrict__ msg,
    const float* __restrict__ deg,
    const float* __restrict__ W,   // [2D][D] row-major
    const float* __restrict__ b,   // [D]
    float*       __restrict__ out, // [N][D]  (may alias h: block only touches own rows)
    int n_nodes)
{
    __shared__ float hc[NB][2 * D];
    const int j    = threadIdx.x;          // output column 0..127
    const int base = blockIdx.x * NB;

    #pragma unroll
    for (int n = 0; n < NB; ++n) {
        const int node = base + n;
        if (node < n_nodes) {
            hc[n][j]     = h[(size_t)node * D + j];
            const float dg = deg[node];
            hc[n][D + j] = msg[(size_t)node * D + j] / fmaxf(dg, 1.0f);
        } else {
            hc[n][j] = 0.0f;
            hc[n][D + j] = 0.0f;
        }
    }
    __syncthreads();

    float acc[NB];
    const float bj = b[j];
    #pragma unroll
    for (int n = 0; n < NB; ++n) acc[n] = bj;

    for (int k = 0; k < 2 * D; ++k) {
        const float w = W[k * D + j];      // coalesced across j
        #pragma unroll
        for (int n = 0; n < NB; ++n)
            acc[n] = fmaf(hc[n][k], w, acc[n]);   // hc broadcast read
    }

    #pragma unroll
    for (int n = 0; n < NB; ++n) {
        const int node = base + n;
        if (node < n_nodes)
            out[(size_t)node * D + j] = fmaxf(acc[n], 0.0f);
    }
}

// ---------------------------------------------------------------------------
extern "C" void kernel_launch(void* const* d_in, const int* in_sizes, int n_in,
                              void* d_out, int out_size, void* d_ws, size_t ws_size,
                              hipStream_t stream)
{
    const float* h    = (const float*)d_in[0];
    const int*   esrc = (const int*)  d_in[1];
    const int*   edst = (const int*)  d_in[2];
    const float* W1   = (const float*)d_in[3];
    const float* b1   = (const float*)d_in[4];
    const float* W2   = (const float*)d_in[5];
    const float* b2   = (const float*)d_in[6];
    float* out = (float*)d_out;

    const int n_nodes = in_sizes[0] / D;
    const int n_edges = in_sizes[1];

    float* msg = (float*)d_ws;                    // [N][D]
    float* deg = msg + (size_t)n_nodes * D;       // [N]

    const int sblocks = 4096;                     // 16384 waves, grid-stride
    const int gblocks = (n_nodes + NB - 1) / NB;

    // ---- layer 1 ----
    hipMemsetAsync(msg, 0, (size_t)(n_nodes * D + n_nodes) * sizeof(float), stream);
    scatter_kernel<true ><<<sblocks, 256, 0, stream>>>(h, esrc, edst, msg, deg, n_edges);
    sage_gemm_kernel<<<gblocks, 128, 0, stream>>>(h, msg, deg, W1, b1, out, n_nodes);

    // ---- layer 2 (deg reused; h1 lives in d_out, GEMM in-place) ----
    hipMemsetAsync(msg, 0, (size_t)n_nodes * D * sizeof(float), stream);
    scatter_kernel<false><<<sblocks, 256, 0, stream>>>(out, esrc, edst, msg, nullptr, n_edges);
    sage_gemm_kernel<<<gblocks, 128, 0, stream>>>(out, msg, deg, W2, b2, out, n_nodes);
}

// Round 2
// 452.719 us; speedup vs baseline: 3.3193x; 3.3193x over previous
//
#include <hip/hip_runtime.h>

#define D 128
#define NB 8

// ---------------- CSR build: histogram ----------------
__global__ __launch_bounds__(256) void hist_kernel(
    const int* __restrict__ dst, int* __restrict__ hist, int n_edges)
{
    int i = blockIdx.x * 256 + threadIdx.x;
    if (i < n_edges) atomicAdd(&hist[dst[i]], 1);
}

// ---------------- CSR build: exclusive scan (single block, 256 thr) --------
__global__ __launch_bounds__(256) void scan_kernel(
    const int* __restrict__ hist, int* __restrict__ row_start,
    int* __restrict__ cursor, int n)
{
    __shared__ int wsum[4];
    const int tid = threadIdx.x, lane = tid & 63, w = tid >> 6;
    int running = 0;
    const int nchunk = (n + 1023) >> 10;
    for (int c = 0; c < nchunk; ++c) {
        const int base = c * 1024 + tid * 4;
        int v0 = (base + 0 < n) ? hist[base + 0] : 0;
        int v1 = (base + 1 < n) ? hist[base + 1] : 0;
        int v2 = (base + 2 < n) ? hist[base + 2] : 0;
        int v3 = (base + 3 < n) ? hist[base + 3] : 0;
        const int s1 = v0 + v1, s2 = s1 + v2, s3 = s2 + v3;
        int incl = s3;
        #pragma unroll
        for (int off = 1; off < 64; off <<= 1) {
            int t = __shfl_up(incl, off, 64);
            if (lane >= off) incl += t;
        }
        if (lane == 63) wsum[w] = incl;
        __syncthreads();
        int wp = 0, ct = 0;
        #pragma unroll
        for (int k = 0; k < 4; ++k) { int s = wsum[k]; if (k < w) wp += s; ct += s; }
        const int ex = running + wp + incl - s3;   // exclusive prefix before v0
        if (base + 0 < n) { row_start[base + 0] = ex;      cursor[base + 0] = ex; }
        if (base + 1 < n) { row_start[base + 1] = ex + v0; cursor[base + 1] = ex + v0; }
        if (base + 2 < n) { row_start[base + 2] = ex + s1; cursor[base + 2] = ex + s1; }
        if (base + 3 < n) { row_start[base + 3] = ex + s2; cursor[base + 3] = ex + s2; }
        running += ct;
        __syncthreads();
    }
    if (tid == 0) row_start[n] = running;
}

// ---------------- CSR build: bucket fill ----------------
__global__ __launch_bounds__(256) void fill_kernel(
    const int* __restrict__ src, const int* __restrict__ dst,
    int* __restrict__ cursor, int* __restrict__ adj, int n_edges)
{
    int i = blockIdx.x * 256 + threadIdx.x;
    if (i < n_edges) {
        const int d = dst[i];
        const int pos = atomicAdd(&cursor[d], 1);
        adj[pos] = src[i];
    }
}

// -------- fused: gather-mean + concat + GEMM + bias + relu ----------------
__global__ __launch_bounds__(128) void fused_sage(
    const float* __restrict__ hin, const int* __restrict__ adj,
    const int* __restrict__ row_start, const float* __restrict__ W,
    const float* __restrict__ bias, float* __restrict__ out, int n_nodes)
{
    __shared__ float hc[NB][2 * D];
    const int j = threadIdx.x;               // feature / output column
    const int base = blockIdx.x * NB;

    for (int n = 0; n < NB; ++n) {
        const int node = base + n;
        float own = 0.f, m = 0.f;
        if (node < n_nodes) {
            own = hin[(size_t)node * D + j];
            const int s0 = row_start[node], s1 = row_start[node + 1];
            float sum = 0.f;
            for (int p = s0; p < s1; ++p) {
                const int s = adj[p];
                sum += hin[(size_t)s * D + j];   // 512B coalesced row read
            }
            const int dg = s1 - s0;
            m = sum / (float)(dg > 0 ? dg : 1);
        }
        hc[n][j] = own;
        hc[n][D + j] = m;
    }
    __syncthreads();

    float acc[NB];
    const float bj = bias[j];
    #pragma unroll
    for (int n = 0; n < NB; ++n) acc[n] = bj;

    for (int k = 0; k < 2 * D; ++k) {
        const float wv = W[k * D + j];           // coalesced across j
        #pragma unroll
        for (int n = 0; n < NB; ++n)
            acc[n] = fmaf(hc[n][k], wv, acc[n]); // hc broadcast read
    }

    #pragma unroll
    for (int n = 0; n < NB; ++n) {
        const int node = base + n;
        if (node < n_nodes)
            out[(size_t)node * D + j] = fmaxf(acc[n], 0.f);
    }
}

// ---------------------------------------------------------------------------
extern "C" void kernel_launch(void* const* d_in, const int* in_sizes, int n_in,
                              void* d_out, int out_size, void* d_ws, size_t ws_size,
                              hipStream_t stream)
{
    const float* h    = (const float*)d_in[0];
    const int*   esrc = (const int*)  d_in[1];
    const int*   edst = (const int*)  d_in[2];
    const float* W1   = (const float*)d_in[3];
    const float* b1   = (const float*)d_in[4];
    const float* W2   = (const float*)d_in[5];
    const float* b2   = (const float*)d_in[6];
    float* out = (float*)d_out;

    const int n_nodes = in_sizes[0] / D;
    const int n_edges = in_sizes[1];

    // workspace layout
    float* h1        = (float*)d_ws;                       // [N][D]
    int*   adj       = (int*)(h1 + (size_t)n_nodes * D);   // [E]
    int*   hist      = adj + n_edges;                      // [N]
    int*   row_start = hist + n_nodes;                     // [N+1]
    int*   cursor    = row_start + n_nodes + 1;            // [N]

    const int eblocks = (n_edges + 255) / 256;
    const int gblocks = (n_nodes + NB - 1) / NB;

    // ---- CSR build (once; shared by both layers) ----
    hipMemsetAsync(hist, 0, (size_t)n_nodes * sizeof(int), stream);
    hist_kernel<<<eblocks, 256, 0, stream>>>(edst, hist, n_edges);
    scan_kernel<<<1, 256, 0, stream>>>(hist, row_start, cursor, n_nodes);
    fill_kernel<<<eblocks, 256, 0, stream>>>(esrc, edst, cursor, adj, n_edges);

    // ---- layer 1: h -> h1 (ws) ----
    fused_sage<<<gblocks, 128, 0, stream>>>(h, adj, row_start, W1, b1, h1, n_nodes);
    // ---- layer 2: h1 -> out ----
    fused_sage<<<gblocks, 128, 0, stream>>>(h1, adj, row_start, W2, b2, out, n_nodes);
}

// Round 3
// 425.655 us; speedup vs baseline: 3.5304x; 1.0636x over previous
//
#include <hip/hip_runtime.h>

#define D 128
#define NB 32   // nodes per block

// ---------------- CSR build: histogram ----------------
__global__ __launch_bounds__(256) void hist_kernel(
    const int* __restrict__ dst, int* __restrict__ hist, int n_edges)
{
    int i = blockIdx.x * 256 + threadIdx.x;
    if (i < n_edges) atomicAdd(&hist[dst[i]], 1);
}

// ---------------- CSR build: exclusive scan (single block, 1024 thr) -------
__global__ __launch_bounds__(1024) void scan_kernel(
    const int* __restrict__ hist, int* __restrict__ row_start,
    int* __restrict__ cursor, int n)
{
    __shared__ int wsum[16];
    const int tid = threadIdx.x, lane = tid & 63, w = tid >> 6;
    int running = 0;
    const int nchunk = (n + 4095) >> 12;
    for (int c = 0; c < nchunk; ++c) {
        const int base = c * 4096 + tid * 4;
        int v0 = (base + 0 < n) ? hist[base + 0] : 0;
        int v1 = (base + 1 < n) ? hist[base + 1] : 0;
        int v2 = (base + 2 < n) ? hist[base + 2] : 0;
        int v3 = (base + 3 < n) ? hist[base + 3] : 0;
        const int s1 = v0 + v1, s2 = s1 + v2, s3 = s2 + v3;
        int incl = s3;
        #pragma unroll
        for (int off = 1; off < 64; off <<= 1) {
            int t = __shfl_up(incl, off, 64);
            if (lane >= off) incl += t;
        }
        if (lane == 63) wsum[w] = incl;
        __syncthreads();
        int wp = 0, ct = 0;
        #pragma unroll
        for (int k = 0; k < 16; ++k) { int s = wsum[k]; if (k < w) wp += s; ct += s; }
        const int ex = running + wp + incl - s3;
        if (base + 0 < n) { row_start[base + 0] = ex;      cursor[base + 0] = ex; }
        if (base + 1 < n) { row_start[base + 1] = ex + v0; cursor[base + 1] = ex + v0; }
        if (base + 2 < n) { row_start[base + 2] = ex + s1; cursor[base + 2] = ex + s1; }
        if (base + 3 < n) { row_start[base + 3] = ex + s2; cursor[base + 3] = ex + s2; }
        running += ct;
        __syncthreads();
    }
    if (tid == 0) row_start[n] = running;
}

// ---------------- CSR build: bucket fill ----------------
__global__ __launch_bounds__(256) void fill_kernel(
    const int* __restrict__ src, const int* __restrict__ dst,
    int* __restrict__ cursor, int* __restrict__ adj, int n_edges)
{
    int i = blockIdx.x * 256 + threadIdx.x;
    if (i < n_edges) {
        const int d = dst[i];
        const int pos = atomicAdd(&cursor[d], 1);
        adj[pos] = src[i];
    }
}

// -------- fused: gather-mean + concat + GEMM + bias + relu ----------------
__global__ __launch_bounds__(256) void fused_sage(
    const float* __restrict__ hin, const int* __restrict__ adj,
    const int* __restrict__ row_start, const float* __restrict__ W,
    const float* __restrict__ bias, float* __restrict__ out, int n_nodes)
{
    __shared__ float hc[NB][2 * D];   // 32 KB
    const int tid  = threadIdx.x;
    const int lane = tid & 63;
    const int wave = tid >> 6;        // 0..3
    const int base = blockIdx.x * NB;

    // ---- gather phase: each wave owns 8 nodes; float2 per lane (512B/row) ----
    for (int i = 0; i < 8; ++i) {
        const int nl   = wave * 8 + i;
        const int node = base + nl;
        if (node >= n_nodes) break;
        float2* hrow = reinterpret_cast<float2*>(&hc[nl][0]);
        const float2 own =
            *reinterpret_cast<const float2*>(hin + (size_t)node * D + lane * 2);
        const int s0 = row_start[node], s1 = row_start[node + 1];
        float sx = 0.f, sy = 0.f;
        int p = s0;
        for (; p + 3 < s1; p += 4) {          // 4 independent row loads in flight
            const int sA = adj[p], sB = adj[p + 1], sC = adj[p + 2], sD_ = adj[p + 3];
            const float2 a = *reinterpret_cast<const float2*>(hin + (size_t)sA * D + lane * 2);
            const float2 b = *reinterpret_cast<const float2*>(hin + (size_t)sB * D + lane * 2);
            const float2 c = *reinterpret_cast<const float2*>(hin + (size_t)sC * D + lane * 2);
            const float2 d = *reinterpret_cast<const float2*>(hin + (size_t)sD_ * D + lane * 2);
            sx += (a.x + b.x) + (c.x + d.x);
            sy += (a.y + b.y) + (c.y + d.y);
        }
        for (; p < s1; ++p) {
            const int s = adj[p];
            const float2 a = *reinterpret_cast<const float2*>(hin + (size_t)s * D + lane * 2);
            sx += a.x; sy += a.y;
        }
        const int dg = s1 - s0;
        const float inv = 1.0f / (float)(dg > 0 ? dg : 1);
        hrow[lane]      = own;
        hrow[64 + lane] = make_float2(sx * inv, sy * inv);
    }
    __syncthreads();

    // ---- GEMM phase: thread = (col j, node-half g); 16 nodes per thread ----
    const int j = tid & 127;
    const int g = tid >> 7;           // 0 or 1
    float acc[16];
    const float bj = bias[j];
    #pragma unroll
    for (int n = 0; n < 16; ++n) acc[n] = bj;

    for (int k = 0; k < 2 * D; k += 4) {
        const float w0 = W[(k + 0) * D + j];
        const float w1 = W[(k + 1) * D + j];
        const float w2 = W[(k + 2) * D + j];
        const float w3 = W[(k + 3) * D + j];
        #pragma unroll
        for (int n = 0; n < 16; ++n) {
            const float4 x = *reinterpret_cast<const float4*>(&hc[g * 16 + n][k]);
            acc[n] = fmaf(x.x, w0, fmaf(x.y, w1, fmaf(x.z, w2, fmaf(x.w, w3, acc[n]))));
        }
    }

    #pragma unroll
    for (int n = 0; n < 16; ++n) {
        const int node = base + g * 16 + n;
        if (node < n_nodes)
            out[(size_t)node * D + j] = fmaxf(acc[n], 0.f);
    }
}

// ---------------------------------------------------------------------------
extern "C" void kernel_launch(void* const* d_in, const int* in_sizes, int n_in,
                              void* d_out, int out_size, void* d_ws, size_t ws_size,
                              hipStream_t stream)
{
    const float* h    = (const float*)d_in[0];
    const int*   esrc = (const int*)  d_in[1];
    const int*   edst = (const int*)  d_in[2];
    const float* W1   = (const float*)d_in[3];
    const float* b1   = (const float*)d_in[4];
    const float* W2   = (const float*)d_in[5];
    const float* b2   = (const float*)d_in[6];
    float* out = (float*)d_out;

    const int n_nodes = in_sizes[0] / D;
    const int n_edges = in_sizes[1];

    // workspace layout
    float* h1        = (float*)d_ws;                       // [N][D]
    int*   adj       = (int*)(h1 + (size_t)n_nodes * D);   // [E]
    int*   hist      = adj + n_edges;                      // [N]
    int*   row_start = hist + n_nodes;                     // [N+1]
    int*   cursor    = row_start + n_nodes + 1;            // [N]

    const int eblocks = (n_edges + 255) / 256;
    const int gblocks = (n_nodes + NB - 1) / NB;

    // ---- CSR build (once; shared by both layers) ----
    hipMemsetAsync(hist, 0, (size_t)n_nodes * sizeof(int), stream);
    hist_kernel<<<eblocks, 256, 0, stream>>>(edst, hist, n_edges);
    scan_kernel<<<1, 1024, 0, stream>>>(hist, row_start, cursor, n_nodes);
    fill_kernel<<<eblocks, 256, 0, stream>>>(esrc, edst, cursor, adj, n_edges);

    // ---- layer 1: h -> h1 (ws) ----
    fused_sage<<<gblocks, 256, 0, stream>>>(h, adj, row_start, W1, b1, h1, n_nodes);
    // ---- layer 2: h1 -> out ----
    fused_sage<<<gblocks, 256, 0, stream>>>(h1, adj, row_start, W2, b2, out, n_nodes);
}